// Round 16
// baseline (1153.689 us; speedup 1.0000x reference)
//
#include <hip/hip_runtime.h>
#include <stdint.h>

typedef __bf16 bf16x8 __attribute__((ext_vector_type(8)));
typedef float f32x4 __attribute__((ext_vector_type(4)));
typedef float f4v __attribute__((ext_vector_type(4)));
typedef unsigned int u32x4 __attribute__((ext_vector_type(4)));
typedef unsigned short u16;

__device__ __forceinline__ u16 f2bf(float f) {
  uint32_t u = __float_as_uint(f);
  u += 0x7fffu + ((u >> 16) & 1u);
  return (u16)(u >> 16);
}
__device__ __forceinline__ float bf2f(u16 h) {
  return __uint_as_float(((uint32_t)h) << 16);
}
__device__ __forceinline__ ushort4 cvt4(float4 v) {
  return make_ushort4(f2bf(v.x), f2bf(v.y), f2bf(v.z), f2bf(v.w));
}
__device__ __forceinline__ void acc8(uint4 v, float* a) {
  a[0] += bf2f((u16)(v.x & 0xffff)); a[1] += bf2f((u16)(v.x >> 16));
  a[2] += bf2f((u16)(v.y & 0xffff)); a[3] += bf2f((u16)(v.y >> 16));
  a[4] += bf2f((u16)(v.z & 0xffff)); a[5] += bf2f((u16)(v.z >> 16));
  a[6] += bf2f((u16)(v.w & 0xffff)); a[7] += bf2f((u16)(v.w >> 16));
}

__device__ __forceinline__ f32x4 MFMA(bf16x8 a, bf16x8 b, f32x4 c) {
  return __builtin_amdgcn_mfma_f32_16x16x32_bf16(a, b, c, 0, 0, 0);
}

// x (f32) -> xbf (bf16), one-shot pre-pass. 8 elems/thread.
__global__ void xcvt_kernel(const float* __restrict__ x, u16* __restrict__ xbf, int total8) {
  int t = blockIdx.x * 256 + threadIdx.x;
  if (t >= total8) return;
  const float4* p = (const float4*)(x + (size_t)t * 8);
  float4 a = p[0], b = p[1];
  uint4 pk;
  pk.x = (uint32_t)f2bf(a.x) | ((uint32_t)f2bf(a.y) << 16);
  pk.y = (uint32_t)f2bf(a.z) | ((uint32_t)f2bf(a.w) << 16);
  pk.z = (uint32_t)f2bf(b.x) | ((uint32_t)f2bf(b.y) << 16);
  pk.w = (uint32_t)f2bf(b.z) | ((uint32_t)f2bf(b.w) << 16);
  *(uint4*)(xbf + (size_t)t * 8) = pk;
}

// All 4 weight matrices packed in one launch. Thread segments:
// [0,6144): eb_w1 K=384 | [6144,8192): eb_w2 K=128 | [8192,12288): nb_w1 K=256 | [12288,14336): nb_w2 K=128
__global__ void pack_all_kernel(const float* __restrict__ w1e, const float* __restrict__ w2e,
                                const float* __restrict__ w1n, const float* __restrict__ w2n,
                                u16* __restrict__ p1e, u16* __restrict__ p2e,
                                u16* __restrict__ p1n, u16* __restrict__ p2n) {
  int t = blockIdx.x * 256 + threadIdx.x;
  const float* W;
  u16* dst;
  if (t < 6144) { W = w1e; dst = p1e; }
  else if (t < 8192) { W = w2e; dst = p2e; t -= 6144; }
  else if (t < 12288) { W = w1n; dst = p1n; t -= 8192; }
  else if (t < 14336) { W = w2n; dst = p2n; t -= 12288; }
  else return;
  int l = t & 63;
  int cf = (t >> 6) & 7;
  int ks = t >> 9;
  int kb = ks * 32 + ((l >> 4) << 3);
  int col = cf * 16 + (l & 15);
  u16 o[8];
#pragma unroll
  for (int j = 0; j < 8; ++j) o[j] = f2bf(W[(size_t)(kb + j) * 128 + col]);
  uint4 v;
  v.x = (uint32_t)o[0] | ((uint32_t)o[1] << 16);
  v.y = (uint32_t)o[2] | ((uint32_t)o[3] << 16);
  v.z = (uint32_t)o[4] | ((uint32_t)o[5] << 16);
  v.w = (uint32_t)o[6] | ((uint32_t)o[7] << 16);
  *(uint4*)(dst + (size_t)t * 8) = v;
}

// ---------------- Multi-block CSR scan (proven R7-R15) ----------------
__global__ void scan1_kernel(const int* __restrict__ cnt, int* __restrict__ bsum, int N) {
  const int b = blockIdx.x, t = threadIdx.x;
  const int lo = b * 2048 + t * 8;
  int s = 0;
#pragma unroll
  for (int i = 0; i < 8; ++i) {
    int idx = lo + i;
    if (idx < N) s += cnt[idx];
  }
  __shared__ int red[256];
  red[t] = s;
  __syncthreads();
  for (int off = 128; off; off >>= 1) {
    if (t < off) red[t] += red[t + off];
    __syncthreads();
  }
  if (t == 0) bsum[b] = red[0];
}

__global__ void scan2_kernel(int* __restrict__ bsum, int* __restrict__ roff, int NB, int N, int E) {
  __shared__ int p[512];
  const int t = threadIdx.x;
  p[t] = (t < NB) ? bsum[t] : 0;
  __syncthreads();
  for (int off = 1; off < 512; off <<= 1) {
    int v = (t >= off) ? p[t - off] : 0;
    __syncthreads();
    p[t] += v;
    __syncthreads();
  }
  if (t < NB) bsum[t] = (t == 0) ? 0 : p[t - 1];
  if (t == 0) roff[N] = E;
}

__global__ void scan3_kernel(const int* __restrict__ cnt, const int* __restrict__ bsum,
                             int* __restrict__ roff, int* __restrict__ cur, int N) {
  const int b = blockIdx.x, t = threadIdx.x;
  const int lo = b * 2048 + t * 8;
  int v[8];
  int s = 0;
#pragma unroll
  for (int i = 0; i < 8; ++i) {
    int idx = lo + i;
    v[i] = (idx < N) ? cnt[idx] : 0;
    s += v[i];
  }
  __shared__ int p[256];
  p[t] = s;
  __syncthreads();
  for (int off = 1; off < 256; off <<= 1) {
    int vv = (t >= off) ? p[t - off] : 0;
    __syncthreads();
    p[t] += vv;
    __syncthreads();
  }
  int base = bsum[b] + ((t == 0) ? 0 : p[t - 1]);
#pragma unroll
  for (int i = 0; i < 8; ++i) {
    int idx = lo + i;
    if (idx < N) {
      roff[idx] = base;
      cur[idx] = base;
      base += v[i];
    }
  }
}

__global__ void fill_kernel(const int* __restrict__ ei, int* __restrict__ cur,
                            int* __restrict__ elist, int E) {
  int e = blockIdx.x * 256 + threadIdx.x;
  if (e < E) {
    int p = atomicAdd(&cur[ei[E + e]], 1);
    elist[p] = e;
  }
}

// stage helpers: thread (r = tid>>2, j = tid&3) covers f32 cols 4*(j+4i), i=0..7
__device__ __forceinline__ void stage_issue(const float4* __restrict__ src, int j, float4 v[8]) {
#pragma unroll
  for (int i = 0; i < 8; ++i) v[i] = src[j + 4 * i];
}
__device__ __forceinline__ void stage_zero(float4 v[8]) {
#pragma unroll
  for (int i = 0; i < 8; ++i) v[i] = make_float4(0.f, 0.f, 0.f, 0.f);
}
__device__ __forceinline__ void stage_write(u16* __restrict__ dst, int r, int j, const float4 v[8]) {
#pragma unroll
  for (int i = 0; i < 8; ++i) *(ushort4*)(dst + r * 136 + (j + 4 * i) * 4) = cvt4(v[i]);
}
// bf16 variants: slot j+4i of a 128-u16 row
__device__ __forceinline__ void stage_issue_bf(const ushort4* __restrict__ src, int j, ushort4 v[8]) {
#pragma unroll
  for (int i = 0; i < 8; ++i) v[i] = src[j + 4 * i];
}
__device__ __forceinline__ void stage_zero_bf(ushort4 v[8]) {
#pragma unroll
  for (int i = 0; i < 8; ++i) v[i] = make_ushort4(0, 0, 0, 0);
}
__device__ __forceinline__ void stage_write_bf(u16* __restrict__ dst, int r, int j, const ushort4 v[8]) {
#pragma unroll
  for (int i = 0; i < 8; ++i) *(ushort4*)(dst + r * 136 + (j + 4 * i) * 4) = v[i];
}

// NRF row-fragments x 2 col-fragments of MFMA over 4 K-steps.
template <int ASTRIDE, int NRF>
__device__ __forceinline__ void gemm4(const u16* __restrict__ abase, const u16* __restrict__ pw,
                                      int ksbase, int w, int lane, f32x4 acc[NRF][2]) {
#pragma unroll
  for (int ks = 0; ks < 4; ++ks) {
    bf16x8 b0 = *(const bf16x8*)(pw + ((size_t)((ksbase + ks) * 8 + w * 2 + 0) * 64 + lane) * 8);
    bf16x8 b1 = *(const bf16x8*)(pw + ((size_t)((ksbase + ks) * 8 + w * 2 + 1) * 64 + lane) * 8);
#pragma unroll
    for (int rf = 0; rf < NRF; ++rf) {
      bf16x8 a = *(const bf16x8*)(abase + rf * (16 * ASTRIDE) + ks * 32);
      acc[rf][0] = MFMA(a, b0, acc[rf][0]);
      acc[rf][1] = MFMA(a, b1, acc[rf][1]);
    }
  }
}

// ---------------- Edge kernel (R15 + non-temporal streaming stores) ----------------
// MODE 0: atomicAdd o into agg (f32 x path, scalar stores). MODE 1: vectorized out_edge (+count).
// MODE 2: + bf16 emsg (+count).
template <int MODE>
__global__ __launch_bounds__(256, 4) void edge_kernel(
    const float* __restrict__ x, const u16* __restrict__ xbf,
    const float* __restrict__ edge_attr,
    const int* __restrict__ ei,
    const u16* __restrict__ pw1, const u16* __restrict__ pw2,
    const float* __restrict__ b1, const float* __restrict__ b2,
    const float* __restrict__ gln, const float* __restrict__ bln,
    float* __restrict__ out_edge, float* __restrict__ agg,
    u16* __restrict__ emsg, int* __restrict__ cnt, int E) {
  alignas(16) __shared__ u16 sLds[2 * 64 * 136];
  u16* buf0 = sLds;
  u16* buf1 = sLds + 64 * 136;
  float* sY = (float*)sLds;  // [64][132] f32 = 33792 B <= 34816 B

  const int tid = threadIdx.x;
  const int w = tid >> 6;
  const int lane = tid & 63;
  const int eBase = blockIdx.x * 64;
  const int r = tid >> 2, j = tid & 3;
  const int e0 = eBase + r;
  const bool ev = (e0 < E);
  const int e = ev ? e0 : 0;
  const int s = ei[e];
  const int d = ei[E + e];

  // fused degree count (CSR modes): one atomic per edge (proven R7-R15)
  if (MODE >= 1 && ev && j == 0) atomicAdd(&cnt[d], 1);

  const u16* a0 = buf0 + (lane & 15) * 136 + ((lane >> 4) << 3);
  const u16* a1 = buf1 + (lane & 15) * 136 + ((lane >> 4) << 3);

  float4 v[8];

  // ---- Phase A: stage chunk0 = x[src] -> buf0
  if (MODE >= 1) {
    ushort4 vb[8];
    if (ev) stage_issue_bf((const ushort4*)(xbf + (size_t)s * 128), j, vb); else stage_zero_bf(vb);
    stage_write_bf(buf0, r, j, vb);
  } else {
    if (ev) stage_issue((const float4*)(x + (size_t)s * 128), j, v); else stage_zero(v);
    stage_write(buf0, r, j, v);
  }
  __syncthreads();

  f32x4 acc[4][2];
#pragma unroll
  for (int rf = 0; rf < 4; ++rf)
#pragma unroll
    for (int cf = 0; cf < 2; ++cf) acc[rf][cf] = 0.f;

  // ---- Phase B: issue chunk1 loads (x[dst]); GEMM ks0-3 on buf0; write buf1 late
  if (MODE >= 1) {
    ushort4 vb[8];
    if (ev) stage_issue_bf((const ushort4*)(xbf + (size_t)d * 128), j, vb); else stage_zero_bf(vb);
    gemm4<136, 4>(a0, pw1, 0, w, lane, acc);
    stage_write_bf(buf1, r, j, vb);
  } else {
    if (ev) stage_issue((const float4*)(x + (size_t)d * 128), j, v); else stage_zero(v);
    gemm4<136, 4>(a0, pw1, 0, w, lane, acc);
    stage_write(buf1, r, j, v);
  }
  __syncthreads();

  // ---- Phase C: issue chunk2 loads (edge_attr); GEMM ks4-7 on buf1; write buf0 late
  if (ev) stage_issue((const float4*)(edge_attr + (size_t)e * 128), j, v); else stage_zero(v);
  gemm4<136, 4>(a1, pw1, 4, w, lane, acc);
  stage_write(buf0, r, j, v);
  __syncthreads();

  // ---- Phase D: GEMM ks8-11 on buf0; bias1 + SiLU -> sH (= buf1)
  gemm4<136, 4>(a0, pw1, 8, w, lane, acc);
  {
    const int colb = w * 32;
#pragma unroll
    for (int cf = 0; cf < 2; ++cf) {
      const int col = colb + cf * 16 + (lane & 15);
      const float bias = b1[col];
#pragma unroll
      for (int rf = 0; rf < 4; ++rf) {
#pragma unroll
        for (int jj = 0; jj < 4; ++jj) {
          const int row = rf * 16 + ((lane >> 4) << 2) + jj;
          float vv = acc[rf][cf][jj] + bias;
          float h = vv / (1.f + __expf(-vv));
          buf1[row * 136 + col] = f2bf(h);
        }
      }
    }
  }
  __syncthreads();

  // ---- Phase E: GEMM2 on sH (buf1); read bf16 edge_attr residual from buf0
  // MODE>=1: contiguous (lane j owns cols 32j..32j+31); MODE 0: strided (R13 layout)
  f32x4 acc2[4][2];
#pragma unroll
  for (int rf = 0; rf < 4; ++rf)
#pragma unroll
    for (int cf = 0; cf < 2; ++cf) acc2[rf][cf] = 0.f;
  gemm4<136, 4>(a1, pw2, 0, w, lane, acc2);
  float ea[32];
  if (MODE >= 1) {
#pragma unroll
    for (int t = 0; t < 32; ++t) ea[t] = bf2f(buf0[r * 136 + 32 * j + t]);
  } else {
#pragma unroll
    for (int i = 0; i < 32; ++i) ea[i] = bf2f(buf0[r * 136 + j + 4 * i]);
  }
  __syncthreads();

  // ---- Phase F: Y = acc2 + b2 -> sY (f32, stride 132)
  {
    const int colb = w * 32;
#pragma unroll
    for (int cf = 0; cf < 2; ++cf) {
      const int col = colb + cf * 16 + (lane & 15);
      const float bias = b2[col];
#pragma unroll
      for (int rf = 0; rf < 4; ++rf) {
#pragma unroll
        for (int jj = 0; jj < 4; ++jj) {
          const int row = rf * 16 + ((lane >> 4) << 2) + jj;
          sY[row * 132 + col] = acc2[rf][cf][jj] + bias;
        }
      }
    }
  }
  __syncthreads();

  // ---- Phase G: LayerNorm (lane j reduces its strided cols {j, j+4, ...}; proven math)
  if (MODE == 0) {
    if (ev) {
      float vals[32];
      float sum = 0.f, sq = 0.f;
#pragma unroll
      for (int i = 0; i < 32; ++i) {
        float vv = sY[r * 132 + j + i * 4];
        vals[i] = vv;
        sum += vv;
        sq += vv * vv;
      }
      sum += __shfl_xor(sum, 1);
      sum += __shfl_xor(sum, 2);
      sq += __shfl_xor(sq, 1);
      sq += __shfl_xor(sq, 2);
      const float mu = sum * (1.f / 128.f);
      const float rs = rsqrtf(sq * (1.f / 128.f) - mu * mu + 1e-5f);
      float* orow = out_edge + (size_t)e * 128;
      float* aggrow = agg + (size_t)d * 128;
#pragma unroll
      for (int i = 0; i < 32; ++i) {
        const int c = j + i * 4;
        const float o = (vals[i] - mu) * rs * gln[c] + bln[c];
        orow[c] = ea[i] + o;
        atomicAdd(aggrow + c, o);
      }
    }
  } else {
    // MODE >= 1: compute o into sY (own strided cells), then vectorized NT stores after barrier
    if (ev) {
      float vals[32];
      float sum = 0.f, sq = 0.f;
#pragma unroll
      for (int i = 0; i < 32; ++i) {
        float vv = sY[r * 132 + j + i * 4];
        vals[i] = vv;
        sum += vv;
        sq += vv * vv;
      }
      sum += __shfl_xor(sum, 1);
      sum += __shfl_xor(sum, 2);
      sq += __shfl_xor(sq, 1);
      sq += __shfl_xor(sq, 2);
      const float mu = sum * (1.f / 128.f);
      const float rs = rsqrtf(sq * (1.f / 128.f) - mu * mu + 1e-5f);
#pragma unroll
      for (int i = 0; i < 32; ++i) {
        const int c = j + i * 4;
        sY[r * 132 + c] = (vals[i] - mu) * rs * gln[c] + bln[c];  // own cell, read-then-write
      }
    }
    __syncthreads();
    if (ev) {
      float* orow = out_edge + (size_t)e * 128 + 32 * j;
      u16* emrow = emsg + (size_t)e * 128 + 32 * j;
#pragma unroll
      for (int t = 0; t < 4; ++t) {
        float4 lo = *(const float4*)(sY + r * 132 + 32 * j + 8 * t);  // proven R13/R15 addresses
        float4 hi = *(const float4*)(sY + r * 132 + 32 * j + 8 * t + 4);
        f4v r0, r1;
        r0.x = ea[8 * t + 0] + lo.x; r0.y = ea[8 * t + 1] + lo.y;
        r0.z = ea[8 * t + 2] + lo.z; r0.w = ea[8 * t + 3] + lo.w;
        r1.x = ea[8 * t + 4] + hi.x; r1.y = ea[8 * t + 5] + hi.y;
        r1.z = ea[8 * t + 6] + hi.z; r1.w = ea[8 * t + 7] + hi.w;
        __builtin_nontemporal_store(r0, (f4v*)(orow + 8 * t));
        __builtin_nontemporal_store(r1, (f4v*)(orow + 8 * t + 4));
        if (MODE == 2) {
          u32x4 pk;
          pk.x = (uint32_t)f2bf(lo.x) | ((uint32_t)f2bf(lo.y) << 16);
          pk.y = (uint32_t)f2bf(lo.z) | ((uint32_t)f2bf(lo.w) << 16);
          pk.z = (uint32_t)f2bf(hi.x) | ((uint32_t)f2bf(hi.y) << 16);
          pk.w = (uint32_t)f2bf(hi.z) | ((uint32_t)f2bf(hi.w) << 16);
          __builtin_nontemporal_store(pk, (u32x4*)(emrow + 8 * t));
        }
      }
    }
  }
}

// ---------------- Node kernel (R15-proven; NT outx stores) ----------------
template <int MODE>
__global__ __launch_bounds__(256, 4) void node_kernel(
    const float* __restrict__ x, const u16* __restrict__ xbf,
    const float* __restrict__ aggin,
    const int* __restrict__ roff, const int* __restrict__ elist,
    const u16* __restrict__ emsg,
    const float* __restrict__ out_edge_ro, const float* __restrict__ edge_attr,
    const u16* __restrict__ pw1, const u16* __restrict__ pw2,
    const float* __restrict__ b1, const float* __restrict__ b2,
    const float* __restrict__ gln, const float* __restrict__ bln,
    float* __restrict__ outx, int N) {
  alignas(16) __shared__ u16 sN[64 * 392];  // 50176 B -> 3 blocks/CU
  float* sY = (float*)sN;                    // [64][133] f32 = 34048 B

  const int tid = threadIdx.x;
  const int w = tid >> 6;
  const int lane = tid & 63;
  const int nBase = blockIdx.x * 64;
  const int r = tid >> 2, j = tid & 3;
  const int n0 = nBase + r;
  const bool nv = (n0 < N);
  const int n = nv ? n0 : 0;

  // ---- Phase A: stage [x | agg_hi | agg_lo] -> sN (bf16)
  {
    if (MODE >= 1) {
      ushort4 vb[8];
      if (nv) stage_issue_bf((const ushort4*)(xbf + (size_t)n * 128), j, vb); else stage_zero_bf(vb);
#pragma unroll
      for (int i = 0; i < 8; ++i) *(ushort4*)(sN + r * 392 + (j + 4 * i) * 4) = vb[i];
    } else {
      float4 v[8];
      if (nv) stage_issue((const float4*)(x + (size_t)n * 128), j, v); else stage_zero(v);
#pragma unroll
      for (int i = 0; i < 8; ++i) *(ushort4*)(sN + r * 392 + (j + 4 * i) * 4) = cvt4(v[i]);
    }
    if (MODE == 0) {
      float4 v[8];
      if (nv) stage_issue((const float4*)(aggin + (size_t)n * 128), j, v); else stage_zero(v);
#pragma unroll
      for (int i = 0; i < 8; ++i) {
        ushort4 h4 = cvt4(v[i]);
        float4 lo4 = make_float4(v[i].x - bf2f(h4.x), v[i].y - bf2f(h4.y),
                                 v[i].z - bf2f(h4.z), v[i].w - bf2f(h4.w));
        *(ushort4*)(sN + r * 392 + 128 + (j + 4 * i) * 4) = h4;
        *(ushort4*)(sN + r * 392 + 256 + (j + 4 * i) * 4) = cvt4(lo4);
      }
    } else {
      // CSR gather: lane j accumulates cols [32j, 32j+32) over incident edges
      float a[32];
#pragma unroll
      for (int i = 0; i < 32; ++i) a[i] = 0.f;
      if (nv) {
        const int k0 = roff[n];
        const int k1 = roff[n + 1];
        if (MODE == 2) {
          const u16* base = emsg + 32 * j;
          for (int k = k0; k < k1; ++k) {
            const int eid = elist[k];
            const uint4* p = (const uint4*)(base + (size_t)eid * 128);
            uint4 q0 = p[0], q1 = p[1], q2 = p[2], q3 = p[3];
            acc8(q0, a + 0); acc8(q1, a + 8); acc8(q2, a + 16); acc8(q3, a + 24);
          }
        } else {  // MODE 1: o = out_edge - edge_attr (both f32), via elist
          for (int k = k0; k < k1; ++k) {
            const int eid = elist[k];
            const float4* po = (const float4*)(out_edge_ro + (size_t)eid * 128 + 32 * j);
            const float4* pa = (const float4*)(edge_attr + (size_t)eid * 128 + 32 * j);
#pragma unroll
            for (int qq = 0; qq < 8; ++qq) {
              float4 ov = po[qq], av = pa[qq];
              a[4 * qq + 0] += ov.x - av.x;
              a[4 * qq + 1] += ov.y - av.y;
              a[4 * qq + 2] += ov.z - av.z;
              a[4 * qq + 3] += ov.w - av.w;
            }
          }
        }
      }
      // hi/lo split: agg_hi = bf16(a), agg_lo = bf16(a - f32(agg_hi))
#pragma unroll
      for (int t = 0; t < 8; ++t) {
        ushort4 h4, l4;
#pragma unroll
        for (int qq = 0; qq < 4; ++qq) {
          const float av = a[4 * t + qq];
          const u16 hb = f2bf(av);
          const float lv = av - bf2f(hb);
          ((u16*)&h4)[qq] = hb;
          ((u16*)&l4)[qq] = f2bf(lv);
        }
        *(ushort4*)(sN + r * 392 + 128 + 32 * j + 4 * t) = h4;
        *(ushort4*)(sN + r * 392 + 256 + 32 * j + 4 * t) = l4;
      }
    }
  }
  __syncthreads();

  // ---- Phase B: GEMM1 [64x384] @ ([256x128] with agg slice applied to hi and lo)
  f32x4 acc[4][2];
#pragma unroll
  for (int rf = 0; rf < 4; ++rf)
#pragma unroll
    for (int cf = 0; cf < 2; ++cf) acc[rf][cf] = 0.f;
  {
    const u16* abase = sN + (lane & 15) * 392 + ((lane >> 4) << 3);
    gemm4<392, 4>(abase, pw1, 0, w, lane, acc);        // x half (W ks 0-3)
    gemm4<392, 4>(abase + 128, pw1, 4, w, lane, acc);  // agg_hi (W ks 4-7)
    gemm4<392, 4>(abase + 256, pw1, 4, w, lane, acc);  // agg_lo (same W ks 4-7)
  }
  __syncthreads();

  // ---- Phase C: bias1 + SiLU -> sH (overlays sN, stride 136)
  {
    const int colb = w * 32;
#pragma unroll
    for (int cf = 0; cf < 2; ++cf) {
      const int col = colb + cf * 16 + (lane & 15);
      const float bias = b1[col];
#pragma unroll
      for (int rf = 0; rf < 4; ++rf) {
#pragma unroll
        for (int jj = 0; jj < 4; ++jj) {
          const int row = rf * 16 + ((lane >> 4) << 2) + jj;
          float vv = acc[rf][cf][jj] + bias;
          float h = vv / (1.f + __expf(-vv));
          sN[row * 136 + col] = f2bf(h);
        }
      }
    }
  }
  __syncthreads();

  // ---- Phase D: GEMM2 [64x128] @ [128x128]
  f32x4 acc2[4][2];
#pragma unroll
  for (int rf = 0; rf < 4; ++rf)
#pragma unroll
    for (int cf = 0; cf < 2; ++cf) acc2[rf][cf] = 0.f;
  {
    const u16* abase = sN + (lane & 15) * 136 + ((lane >> 4) << 3);
    gemm4<136, 4>(abase, pw2, 0, w, lane, acc2);
  }
  __syncthreads();

  // ---- Phase E: Y = acc2 + b2 -> sY (stride 133)
  {
    const int colb = w * 32;
#pragma unroll
    for (int cf = 0; cf < 2; ++cf) {
      const int col = colb + cf * 16 + (lane & 15);
      const float bias = b2[col];
#pragma unroll
      for (int rf = 0; rf < 4; ++rf) {
#pragma unroll
        for (int jj = 0; jj < 4; ++jj) {
          const int row = rf * 16 + ((lane >> 4) << 2) + jj;
          sY[row * 133 + col] = acc2[rf][cf][jj] + bias;
        }
      }
    }
  }
  __syncthreads();

  // ---- Phase F: LayerNorm + residual; lane j owns cols [32j, 32j+32)
  if (nv) {
    const int cb = 32 * j;
    float vals[32];
    float sum = 0.f, sq = 0.f;
#pragma unroll
    for (int i = 0; i < 32; ++i) {
      float vv = sY[r * 133 + cb + i];
      vals[i] = vv;
      sum += vv;
      sq += vv * vv;
    }
    sum += __shfl_xor(sum, 1);
    sum += __shfl_xor(sum, 2);
    sq += __shfl_xor(sq, 1);
    sq += __shfl_xor(sq, 2);
    const float mu = sum * (1.f / 128.f);
    const float rs = rsqrtf(sq * (1.f / 128.f) - mu * mu + 1e-5f);
    const float* xrow = x + (size_t)n * 128 + cb;
    float* orow = outx + (size_t)n * 128 + cb;
#pragma unroll
    for (int qq = 0; qq < 8; ++qq) {
      float4 xv = *(const float4*)(xrow + 4 * qq);
      f4v t4;
      t4.x = xv.x + (vals[4 * qq + 0] - mu) * rs * gln[cb + 4 * qq + 0] + bln[cb + 4 * qq + 0];
      t4.y = xv.y + (vals[4 * qq + 1] - mu) * rs * gln[cb + 4 * qq + 1] + bln[cb + 4 * qq + 1];
      t4.z = xv.z + (vals[4 * qq + 2] - mu) * rs * gln[cb + 4 * qq + 2] + bln[cb + 4 * qq + 2];
      t4.w = xv.w + (vals[4 * qq + 3] - mu) * rs * gln[cb + 4 * qq + 3] + bln[cb + 4 * qq + 3];
      __builtin_nontemporal_store(t4, (f4v*)(orow + 4 * qq));
    }
  }
}

extern "C" void kernel_launch(void* const* d_in, const int* in_sizes, int n_in,
                              void* d_out, int out_size, void* d_ws, size_t ws_size,
                              hipStream_t stream) {
  const float* x = (const float*)d_in[0];
  const float* edge_attr = (const float*)d_in[1];
  const int* ei = (const int*)d_in[2];
  const float* eb_w1 = (const float*)d_in[3];
  const float* eb_b1 = (const float*)d_in[4];
  const float* eb_w2 = (const float*)d_in[5];
  const float* eb_b2 = (const float*)d_in[6];
  const float* eb_g = (const float*)d_in[7];
  const float* eb_beta = (const float*)d_in[8];
  const float* nb_w1 = (const float*)d_in[9];
  const float* nb_b1 = (const float*)d_in[10];
  const float* nb_w2 = (const float*)d_in[11];
  const float* nb_b2 = (const float*)d_in[12];
  const float* nb_g = (const float*)d_in[13];
  const float* nb_beta = (const float*)d_in[14];

  const int N = in_sizes[0] / 128;
  const int E = in_sizes[1] / 128;

  float* out = (float*)d_out;
  float* agg = out;  // MODE 0 only
  float* out_edge = out + (size_t)N * 128;

  // ws layout: packed weights | xbf (bf16 x) | CSR (cnt, roff, cur, elist, bsum) | emsg (bf16)
  u16* pw1e = (u16*)d_ws;
  u16* pw2e = pw1e + 384 * 128;
  u16* pw1n = pw2e + 128 * 128;
  u16* pw2n = pw1n + 256 * 128;
  const size_t w_bytes = (size_t)(384 + 128 + 256 + 128) * 128 * 2;  // 229376
  u16* xbf = (u16*)((char*)d_ws + w_bytes);
  const size_t xbf_bytes = (size_t)N * 128 * 2;
  int* cnt = (int*)((char*)d_ws + w_bytes + xbf_bytes);
  int* roff = cnt + N;
  int* cur = roff + N + 1;
  int* elist = cur + N;
  int* bsum = elist + E;
  const size_t csr_bytes = (size_t)4 * (3 * (size_t)N + 1 + (size_t)E + 512);
  size_t em_off = w_bytes + xbf_bytes + csr_bytes;
  em_off = (em_off + 15) & ~(size_t)15;
  u16* emsg = (u16*)((char*)d_ws + em_off);
  const size_t need_emsg = em_off + (size_t)E * 128 * 2;
  const size_t need_csr = w_bytes + xbf_bytes + csr_bytes;
  const int mode = (ws_size >= need_emsg) ? 2 : ((ws_size >= need_csr) ? 1 : 0);

  pack_all_kernel<<<(14336 + 255) / 256, 256, 0, stream>>>(eb_w1, eb_w2, nb_w1, nb_w2,
                                                           pw1e, pw2e, pw1n, pw2n);

  const int eg = (E + 63) / 64, ng = (N + 63) / 64;
  const int NB = (N + 2047) / 2048;  // <= 512 supported

  if (mode >= 1) {
    const int total8 = N * 16;  // N*128/8
    xcvt_kernel<<<(total8 + 255) / 256, 256, 0, stream>>>(x, xbf, total8);
    hipMemsetAsync(cnt, 0, (size_t)N * 4, stream);
    if (mode == 2) {
      edge_kernel<2><<<eg, 256, 0, stream>>>(x, xbf, edge_attr, ei, pw1e, pw2e, eb_b1,
                                             eb_b2, eb_g, eb_beta, out_edge, agg, emsg, cnt, E);
    } else {
      edge_kernel<1><<<eg, 256, 0, stream>>>(x, xbf, edge_attr, ei, pw1e, pw2e, eb_b1,
                                             eb_b2, eb_g, eb_beta, out_edge, agg, emsg, cnt, E);
    }
    scan1_kernel<<<NB, 256, 0, stream>>>(cnt, bsum, N);
    scan2_kernel<<<1, 512, 0, stream>>>(bsum, roff, NB, N, E);
    scan3_kernel<<<NB, 256, 0, stream>>>(cnt, bsum, roff, cur, N);
    fill_kernel<<<(E + 255) / 256, 256, 0, stream>>>(ei, cur, elist, E);
    if (mode == 2) {
      node_kernel<2><<<ng, 256, 0, stream>>>(x, xbf, nullptr, roff, elist, emsg, nullptr,
                                             nullptr, pw1n, pw2n, nb_b1, nb_b2, nb_g,
                                             nb_beta, out, N);
    } else {
      node_kernel<1><<<ng, 256, 0, stream>>>(x, xbf, nullptr, roff, elist, nullptr, out_edge,
                                             edge_attr, pw1n, pw2n, nb_b1, nb_b2, nb_g,
                                             nb_beta, out, N);
    }
  } else {
    hipMemsetAsync(agg, 0, (size_t)N * 128 * sizeof(float), stream);
    edge_kernel<0><<<eg, 256, 0, stream>>>(x, nullptr, edge_attr, ei, pw1e, pw2e, eb_b1,
                                           eb_b2, eb_g, eb_beta, out_edge, agg, emsg, cnt, E);
    node_kernel<0><<<ng, 256, 0, stream>>>(x, nullptr, agg, nullptr, nullptr, nullptr,
                                           nullptr, nullptr, pw1n, pw2n, nb_b1, nb_b2,
                                           nb_g, nb_beta, out, N);
  }
}

// Round 17
// 439.700 us; speedup vs baseline: 2.6238x; 2.6238x over previous
//
#include <hip/hip_runtime.h>
#include <stdint.h>

typedef __bf16 bf16x8 __attribute__((ext_vector_type(8)));
typedef float f32x4 __attribute__((ext_vector_type(4)));
typedef unsigned short u16;

__device__ __forceinline__ u16 f2bf(float f) {
  uint32_t u = __float_as_uint(f);
  u += 0x7fffu + ((u >> 16) & 1u);
  return (u16)(u >> 16);
}
__device__ __forceinline__ float bf2f(u16 h) {
  return __uint_as_float(((uint32_t)h) << 16);
}
__device__ __forceinline__ ushort4 cvt4(float4 v) {
  return make_ushort4(f2bf(v.x), f2bf(v.y), f2bf(v.z), f2bf(v.w));
}
__device__ __forceinline__ void acc8(uint4 v, float* a) {
  a[0] += bf2f((u16)(v.x & 0xffff)); a[1] += bf2f((u16)(v.x >> 16));
  a[2] += bf2f((u16)(v.y & 0xffff)); a[3] += bf2f((u16)(v.y >> 16));
  a[4] += bf2f((u16)(v.z & 0xffff)); a[5] += bf2f((u16)(v.z >> 16));
  a[6] += bf2f((u16)(v.w & 0xffff)); a[7] += bf2f((u16)(v.w >> 16));
}

__device__ __forceinline__ f32x4 MFMA(bf16x8 a, bf16x8 b, f32x4 c) {
  return __builtin_amdgcn_mfma_f32_16x16x32_bf16(a, b, c, 0, 0, 0);
}

// x (f32) -> xbf (bf16), one-shot pre-pass. 8 elems/thread.
__global__ void xcvt_kernel(const float* __restrict__ x, u16* __restrict__ xbf, int total8) {
  int t = blockIdx.x * 256 + threadIdx.x;
  if (t >= total8) return;
  const float4* p = (const float4*)(x + (size_t)t * 8);
  float4 a = p[0], b = p[1];
  uint4 pk;
  pk.x = (uint32_t)f2bf(a.x) | ((uint32_t)f2bf(a.y) << 16);
  pk.y = (uint32_t)f2bf(a.z) | ((uint32_t)f2bf(a.w) << 16);
  pk.z = (uint32_t)f2bf(b.x) | ((uint32_t)f2bf(b.y) << 16);
  pk.w = (uint32_t)f2bf(b.z) | ((uint32_t)f2bf(b.w) << 16);
  *(uint4*)(xbf + (size_t)t * 8) = pk;
}

// All 4 weight matrices packed in one launch. Thread segments:
// [0,6144): eb_w1 K=384 | [6144,8192): eb_w2 K=128 | [8192,12288): nb_w1 K=256 | [12288,14336): nb_w2 K=128
__global__ void pack_all_kernel(const float* __restrict__ w1e, const float* __restrict__ w2e,
                                const float* __restrict__ w1n, const float* __restrict__ w2n,
                                u16* __restrict__ p1e, u16* __restrict__ p2e,
                                u16* __restrict__ p1n, u16* __restrict__ p2n) {
  int t = blockIdx.x * 256 + threadIdx.x;
  const float* W;
  u16* dst;
  if (t < 6144) { W = w1e; dst = p1e; }
  else if (t < 8192) { W = w2e; dst = p2e; t -= 6144; }
  else if (t < 12288) { W = w1n; dst = p1n; t -= 8192; }
  else if (t < 14336) { W = w2n; dst = p2n; t -= 12288; }
  else return;
  int l = t & 63;
  int cf = (t >> 6) & 7;
  int ks = t >> 9;
  int kb = ks * 32 + ((l >> 4) << 3);
  int col = cf * 16 + (l & 15);
  u16 o[8];
#pragma unroll
  for (int j = 0; j < 8; ++j) o[j] = f2bf(W[(size_t)(kb + j) * 128 + col]);
  uint4 v;
  v.x = (uint32_t)o[0] | ((uint32_t)o[1] << 16);
  v.y = (uint32_t)o[2] | ((uint32_t)o[3] << 16);
  v.z = (uint32_t)o[4] | ((uint32_t)o[5] << 16);
  v.w = (uint32_t)o[6] | ((uint32_t)o[7] << 16);
  *(uint4*)(dst + (size_t)t * 8) = v;
}

// ---------------- Multi-block CSR scan (proven R7-R15) ----------------
__global__ void scan1_kernel(const int* __restrict__ cnt, int* __restrict__ bsum, int N) {
  const int b = blockIdx.x, t = threadIdx.x;
  const int lo = b * 2048 + t * 8;
  int s = 0;
#pragma unroll
  for (int i = 0; i < 8; ++i) {
    int idx = lo + i;
    if (idx < N) s += cnt[idx];
  }
  __shared__ int red[256];
  red[t] = s;
  __syncthreads();
  for (int off = 128; off; off >>= 1) {
    if (t < off) red[t] += red[t + off];
    __syncthreads();
  }
  if (t == 0) bsum[b] = red[0];
}

__global__ void scan2_kernel(int* __restrict__ bsum, int* __restrict__ roff, int NB, int N, int E) {
  __shared__ int p[512];
  const int t = threadIdx.x;
  p[t] = (t < NB) ? bsum[t] : 0;
  __syncthreads();
  for (int off = 1; off < 512; off <<= 1) {
    int v = (t >= off) ? p[t - off] : 0;
    __syncthreads();
    p[t] += v;
    __syncthreads();
  }
  if (t < NB) bsum[t] = (t == 0) ? 0 : p[t - 1];
  if (t == 0) roff[N] = E;
}

__global__ void scan3_kernel(const int* __restrict__ cnt, const int* __restrict__ bsum,
                             int* __restrict__ roff, int* __restrict__ cur, int N) {
  const int b = blockIdx.x, t = threadIdx.x;
  const int lo = b * 2048 + t * 8;
  int v[8];
  int s = 0;
#pragma unroll
  for (int i = 0; i < 8; ++i) {
    int idx = lo + i;
    v[i] = (idx < N) ? cnt[idx] : 0;
    s += v[i];
  }
  __shared__ int p[256];
  p[t] = s;
  __syncthreads();
  for (int off = 1; off < 256; off <<= 1) {
    int vv = (t >= off) ? p[t - off] : 0;
    __syncthreads();
    p[t] += vv;
    __syncthreads();
  }
  int base = bsum[b] + ((t == 0) ? 0 : p[t - 1]);
#pragma unroll
  for (int i = 0; i < 8; ++i) {
    int idx = lo + i;
    if (idx < N) {
      roff[idx] = base;
      cur[idx] = base;
      base += v[i];
    }
  }
}

__global__ void fill_kernel(const int* __restrict__ ei, int* __restrict__ cur,
                            int* __restrict__ elist, int E) {
  int e = blockIdx.x * 256 + threadIdx.x;
  if (e < E) {
    int p = atomicAdd(&cur[ei[E + e]], 1);
    elist[p] = e;
  }
}

// stage helpers: thread (r = tid>>2, j = tid&3) covers f32 cols 4*(j+4i), i=0..7
__device__ __forceinline__ void stage_issue(const float4* __restrict__ src, int j, float4 v[8]) {
#pragma unroll
  for (int i = 0; i < 8; ++i) v[i] = src[j + 4 * i];
}
__device__ __forceinline__ void stage_zero(float4 v[8]) {
#pragma unroll
  for (int i = 0; i < 8; ++i) v[i] = make_float4(0.f, 0.f, 0.f, 0.f);
}
__device__ __forceinline__ void stage_write(u16* __restrict__ dst, int r, int j, const float4 v[8]) {
#pragma unroll
  for (int i = 0; i < 8; ++i) *(ushort4*)(dst + r * 136 + (j + 4 * i) * 4) = cvt4(v[i]);
}
// bf16 variants: slot j+4i of a 128-u16 row
__device__ __forceinline__ void stage_issue_bf(const ushort4* __restrict__ src, int j, ushort4 v[8]) {
#pragma unroll
  for (int i = 0; i < 8; ++i) v[i] = src[j + 4 * i];
}
__device__ __forceinline__ void stage_zero_bf(ushort4 v[8]) {
#pragma unroll
  for (int i = 0; i < 8; ++i) v[i] = make_ushort4(0, 0, 0, 0);
}
__device__ __forceinline__ void stage_write_bf(u16* __restrict__ dst, int r, int j, const ushort4 v[8]) {
#pragma unroll
  for (int i = 0; i < 8; ++i) *(ushort4*)(dst + r * 136 + (j + 4 * i) * 4) = v[i];
}

// NRF row-fragments x 2 col-fragments of MFMA over 4 K-steps.
template <int ASTRIDE, int NRF>
__device__ __forceinline__ void gemm4(const u16* __restrict__ abase, const u16* __restrict__ pw,
                                      int ksbase, int w, int lane, f32x4 acc[NRF][2]) {
#pragma unroll
  for (int ks = 0; ks < 4; ++ks) {
    bf16x8 b0 = *(const bf16x8*)(pw + ((size_t)((ksbase + ks) * 8 + w * 2 + 0) * 64 + lane) * 8);
    bf16x8 b1 = *(const bf16x8*)(pw + ((size_t)((ksbase + ks) * 8 + w * 2 + 1) * 64 + lane) * 8);
#pragma unroll
    for (int rf = 0; rf < NRF; ++rf) {
      bf16x8 a = *(const bf16x8*)(abase + rf * (16 * ASTRIDE) + ks * 32);
      acc[rf][0] = MFMA(a, b0, acc[rf][0]);
      acc[rf][1] = MFMA(a, b1, acc[rf][1]);
    }
  }
}

// ---------------- Edge kernel (R15-proven: plain vectorized stores) ----------------
// MODE 0: atomicAdd o into agg (f32 x path, scalar stores). MODE 1: vectorized out_edge (+count).
// MODE 2: + bf16 emsg (+count).
template <int MODE>
__global__ __launch_bounds__(256, 4) void edge_kernel(
    const float* __restrict__ x, const u16* __restrict__ xbf,
    const float* __restrict__ edge_attr,
    const int* __restrict__ ei,
    const u16* __restrict__ pw1, const u16* __restrict__ pw2,
    const float* __restrict__ b1, const float* __restrict__ b2,
    const float* __restrict__ gln, const float* __restrict__ bln,
    float* __restrict__ out_edge, float* __restrict__ agg,
    u16* __restrict__ emsg, int* __restrict__ cnt, int E) {
  alignas(16) __shared__ u16 sLds[2 * 64 * 136];
  u16* buf0 = sLds;
  u16* buf1 = sLds + 64 * 136;
  float* sY = (float*)sLds;  // [64][132] f32 = 33792 B <= 34816 B

  const int tid = threadIdx.x;
  const int w = tid >> 6;
  const int lane = tid & 63;
  const int eBase = blockIdx.x * 64;
  const int r = tid >> 2, j = tid & 3;
  const int e0 = eBase + r;
  const bool ev = (e0 < E);
  const int e = ev ? e0 : 0;
  const int s = ei[e];
  const int d = ei[E + e];

  // fused degree count (CSR modes): one atomic per edge (proven R7-R15)
  if (MODE >= 1 && ev && j == 0) atomicAdd(&cnt[d], 1);

  const u16* a0 = buf0 + (lane & 15) * 136 + ((lane >> 4) << 3);
  const u16* a1 = buf1 + (lane & 15) * 136 + ((lane >> 4) << 3);

  float4 v[8];

  // ---- Phase A: stage chunk0 = x[src] -> buf0
  if (MODE >= 1) {
    ushort4 vb[8];
    if (ev) stage_issue_bf((const ushort4*)(xbf + (size_t)s * 128), j, vb); else stage_zero_bf(vb);
    stage_write_bf(buf0, r, j, vb);
  } else {
    if (ev) stage_issue((const float4*)(x + (size_t)s * 128), j, v); else stage_zero(v);
    stage_write(buf0, r, j, v);
  }
  __syncthreads();

  f32x4 acc[4][2];
#pragma unroll
  for (int rf = 0; rf < 4; ++rf)
#pragma unroll
    for (int cf = 0; cf < 2; ++cf) acc[rf][cf] = 0.f;

  // ---- Phase B: issue chunk1 loads (x[dst]); GEMM ks0-3 on buf0; write buf1 late
  if (MODE >= 1) {
    ushort4 vb[8];
    if (ev) stage_issue_bf((const ushort4*)(xbf + (size_t)d * 128), j, vb); else stage_zero_bf(vb);
    gemm4<136, 4>(a0, pw1, 0, w, lane, acc);
    stage_write_bf(buf1, r, j, vb);
  } else {
    if (ev) stage_issue((const float4*)(x + (size_t)d * 128), j, v); else stage_zero(v);
    gemm4<136, 4>(a0, pw1, 0, w, lane, acc);
    stage_write(buf1, r, j, v);
  }
  __syncthreads();

  // ---- Phase C: issue chunk2 loads (edge_attr); GEMM ks4-7 on buf1; write buf0 late
  if (ev) stage_issue((const float4*)(edge_attr + (size_t)e * 128), j, v); else stage_zero(v);
  gemm4<136, 4>(a1, pw1, 4, w, lane, acc);
  stage_write(buf0, r, j, v);
  __syncthreads();

  // ---- Phase D: GEMM ks8-11 on buf0; bias1 + SiLU -> sH (= buf1)
  gemm4<136, 4>(a0, pw1, 8, w, lane, acc);
  {
    const int colb = w * 32;
#pragma unroll
    for (int cf = 0; cf < 2; ++cf) {
      const int col = colb + cf * 16 + (lane & 15);
      const float bias = b1[col];
#pragma unroll
      for (int rf = 0; rf < 4; ++rf) {
#pragma unroll
        for (int jj = 0; jj < 4; ++jj) {
          const int row = rf * 16 + ((lane >> 4) << 2) + jj;
          float vv = acc[rf][cf][jj] + bias;
          float h = vv / (1.f + __expf(-vv));
          buf1[row * 136 + col] = f2bf(h);
        }
      }
    }
  }
  __syncthreads();

  // ---- Phase E: GEMM2 on sH (buf1); read bf16 edge_attr residual from buf0
  // MODE>=1: contiguous (lane j owns cols 32j..32j+31); MODE 0: strided (R13 layout)
  f32x4 acc2[4][2];
#pragma unroll
  for (int rf = 0; rf < 4; ++rf)
#pragma unroll
    for (int cf = 0; cf < 2; ++cf) acc2[rf][cf] = 0.f;
  gemm4<136, 4>(a1, pw2, 0, w, lane, acc2);
  float ea[32];
  if (MODE >= 1) {
#pragma unroll
    for (int t = 0; t < 32; ++t) ea[t] = bf2f(buf0[r * 136 + 32 * j + t]);
  } else {
#pragma unroll
    for (int i = 0; i < 32; ++i) ea[i] = bf2f(buf0[r * 136 + j + 4 * i]);
  }
  __syncthreads();

  // ---- Phase F: Y = acc2 + b2 -> sY (f32, stride 132)
  {
    const int colb = w * 32;
#pragma unroll
    for (int cf = 0; cf < 2; ++cf) {
      const int col = colb + cf * 16 + (lane & 15);
      const float bias = b2[col];
#pragma unroll
      for (int rf = 0; rf < 4; ++rf) {
#pragma unroll
        for (int jj = 0; jj < 4; ++jj) {
          const int row = rf * 16 + ((lane >> 4) << 2) + jj;
          sY[row * 132 + col] = acc2[rf][cf][jj] + bias;
        }
      }
    }
  }
  __syncthreads();

  // ---- Phase G: LayerNorm (lane j reduces its strided cols {j, j+4, ...}; proven math)
  if (MODE == 0) {
    if (ev) {
      float vals[32];
      float sum = 0.f, sq = 0.f;
#pragma unroll
      for (int i = 0; i < 32; ++i) {
        float vv = sY[r * 132 + j + i * 4];
        vals[i] = vv;
        sum += vv;
        sq += vv * vv;
      }
      sum += __shfl_xor(sum, 1);
      sum += __shfl_xor(sum, 2);
      sq += __shfl_xor(sq, 1);
      sq += __shfl_xor(sq, 2);
      const float mu = sum * (1.f / 128.f);
      const float rs = rsqrtf(sq * (1.f / 128.f) - mu * mu + 1e-5f);
      float* orow = out_edge + (size_t)e * 128;
      float* aggrow = agg + (size_t)d * 128;
#pragma unroll
      for (int i = 0; i < 32; ++i) {
        const int c = j + i * 4;
        const float o = (vals[i] - mu) * rs * gln[c] + bln[c];
        orow[c] = ea[i] + o;
        atomicAdd(aggrow + c, o);
      }
    }
  } else {
    // MODE >= 1: compute o into sY (own strided cells), then vectorized stores after barrier
    if (ev) {
      float vals[32];
      float sum = 0.f, sq = 0.f;
#pragma unroll
      for (int i = 0; i < 32; ++i) {
        float vv = sY[r * 132 + j + i * 4];
        vals[i] = vv;
        sum += vv;
        sq += vv * vv;
      }
      sum += __shfl_xor(sum, 1);
      sum += __shfl_xor(sum, 2);
      sq += __shfl_xor(sq, 1);
      sq += __shfl_xor(sq, 2);
      const float mu = sum * (1.f / 128.f);
      const float rs = rsqrtf(sq * (1.f / 128.f) - mu * mu + 1e-5f);
#pragma unroll
      for (int i = 0; i < 32; ++i) {
        const int c = j + i * 4;
        sY[r * 132 + c] = (vals[i] - mu) * rs * gln[c] + bln[c];  // own cell, read-then-write
      }
    }
    __syncthreads();
    if (ev) {
      float* orow = out_edge + (size_t)e * 128 + 32 * j;
      u16* emrow = emsg + (size_t)e * 128 + 32 * j;
#pragma unroll
      for (int t = 0; t < 4; ++t) {
        float4 lo = *(const float4*)(sY + r * 132 + 32 * j + 8 * t);  // proven R13/R15 addresses
        float4 hi = *(const float4*)(sY + r * 132 + 32 * j + 8 * t + 4);
        float4 r0 = make_float4(ea[8 * t + 0] + lo.x, ea[8 * t + 1] + lo.y,
                                ea[8 * t + 2] + lo.z, ea[8 * t + 3] + lo.w);
        float4 r1 = make_float4(ea[8 * t + 4] + hi.x, ea[8 * t + 5] + hi.y,
                                ea[8 * t + 6] + hi.z, ea[8 * t + 7] + hi.w);
        *(float4*)(orow + 8 * t) = r0;
        *(float4*)(orow + 8 * t + 4) = r1;
        if (MODE == 2) {
          uint4 pk;
          pk.x = (uint32_t)f2bf(lo.x) | ((uint32_t)f2bf(lo.y) << 16);
          pk.y = (uint32_t)f2bf(lo.z) | ((uint32_t)f2bf(lo.w) << 16);
          pk.z = (uint32_t)f2bf(hi.x) | ((uint32_t)f2bf(hi.y) << 16);
          pk.w = (uint32_t)f2bf(hi.z) | ((uint32_t)f2bf(hi.w) << 16);
          *(uint4*)(emrow + 8 * t) = pk;
        }
      }
    }
  }
}

// ---------------- Node kernel (R15-proven; plain float4 outx stores) ----------------
template <int MODE>
__global__ __launch_bounds__(256, 4) void node_kernel(
    const float* __restrict__ x, const u16* __restrict__ xbf,
    const float* __restrict__ aggin,
    const int* __restrict__ roff, const int* __restrict__ elist,
    const u16* __restrict__ emsg,
    const float* __restrict__ out_edge_ro, const float* __restrict__ edge_attr,
    const u16* __restrict__ pw1, const u16* __restrict__ pw2,
    const float* __restrict__ b1, const float* __restrict__ b2,
    const float* __restrict__ gln, const float* __restrict__ bln,
    float* __restrict__ outx, int N) {
  alignas(16) __shared__ u16 sN[64 * 392];  // 50176 B -> 3 blocks/CU
  float* sY = (float*)sN;                    // [64][133] f32 = 34048 B

  const int tid = threadIdx.x;
  const int w = tid >> 6;
  const int lane = tid & 63;
  const int nBase = blockIdx.x * 64;
  const int r = tid >> 2, j = tid & 3;
  const int n0 = nBase + r;
  const bool nv = (n0 < N);
  const int n = nv ? n0 : 0;

  // ---- Phase A: stage [x | agg_hi | agg_lo] -> sN (bf16)
  {
    if (MODE >= 1) {
      ushort4 vb[8];
      if (nv) stage_issue_bf((const ushort4*)(xbf + (size_t)n * 128), j, vb); else stage_zero_bf(vb);
#pragma unroll
      for (int i = 0; i < 8; ++i) *(ushort4*)(sN + r * 392 + (j + 4 * i) * 4) = vb[i];
    } else {
      float4 v[8];
      if (nv) stage_issue((const float4*)(x + (size_t)n * 128), j, v); else stage_zero(v);
#pragma unroll
      for (int i = 0; i < 8; ++i) *(ushort4*)(sN + r * 392 + (j + 4 * i) * 4) = cvt4(v[i]);
    }
    if (MODE == 0) {
      float4 v[8];
      if (nv) stage_issue((const float4*)(aggin + (size_t)n * 128), j, v); else stage_zero(v);
#pragma unroll
      for (int i = 0; i < 8; ++i) {
        ushort4 h4 = cvt4(v[i]);
        float4 lo4 = make_float4(v[i].x - bf2f(h4.x), v[i].y - bf2f(h4.y),
                                 v[i].z - bf2f(h4.z), v[i].w - bf2f(h4.w));
        *(ushort4*)(sN + r * 392 + 128 + (j + 4 * i) * 4) = h4;
        *(ushort4*)(sN + r * 392 + 256 + (j + 4 * i) * 4) = cvt4(lo4);
      }
    } else {
      // CSR gather: lane j accumulates cols [32j, 32j+32) over incident edges
      float a[32];
#pragma unroll
      for (int i = 0; i < 32; ++i) a[i] = 0.f;
      if (nv) {
        const int k0 = roff[n];
        const int k1 = roff[n + 1];
        if (MODE == 2) {
          const u16* base = emsg + 32 * j;
          for (int k = k0; k < k1; ++k) {
            const int eid = elist[k];
            const uint4* p = (const uint4*)(base + (size_t)eid * 128);
            uint4 q0 = p[0], q1 = p[1], q2 = p[2], q3 = p[3];
            acc8(q0, a + 0); acc8(q1, a + 8); acc8(q2, a + 16); acc8(q3, a + 24);
          }
        } else {  // MODE 1: o = out_edge - edge_attr (both f32), via elist
          for (int k = k0; k < k1; ++k) {
            const int eid = elist[k];
            const float4* po = (const float4*)(out_edge_ro + (size_t)eid * 128 + 32 * j);
            const float4* pa = (const float4*)(edge_attr + (size_t)eid * 128 + 32 * j);
#pragma unroll
            for (int qq = 0; qq < 8; ++qq) {
              float4 ov = po[qq], av = pa[qq];
              a[4 * qq + 0] += ov.x - av.x;
              a[4 * qq + 1] += ov.y - av.y;
              a[4 * qq + 2] += ov.z - av.z;
              a[4 * qq + 3] += ov.w - av.w;
            }
          }
        }
      }
      // hi/lo split: agg_hi = bf16(a), agg_lo = bf16(a - f32(agg_hi))
#pragma unroll
      for (int t = 0; t < 8; ++t) {
        ushort4 h4, l4;
#pragma unroll
        for (int qq = 0; qq < 4; ++qq) {
          const float av = a[4 * t + qq];
          const u16 hb = f2bf(av);
          const float lv = av - bf2f(hb);
          ((u16*)&h4)[qq] = hb;
          ((u16*)&l4)[qq] = f2bf(lv);
        }
        *(ushort4*)(sN + r * 392 + 128 + 32 * j + 4 * t) = h4;
        *(ushort4*)(sN + r * 392 + 256 + 32 * j + 4 * t) = l4;
      }
    }
  }
  __syncthreads();

  // ---- Phase B: GEMM1 [64x384] @ ([256x128] with agg slice applied to hi and lo)
  f32x4 acc[4][2];
#pragma unroll
  for (int rf = 0; rf < 4; ++rf)
#pragma unroll
    for (int cf = 0; cf < 2; ++cf) acc[rf][cf] = 0.f;
  {
    const u16* abase = sN + (lane & 15) * 392 + ((lane >> 4) << 3);
    gemm4<392, 4>(abase, pw1, 0, w, lane, acc);        // x half (W ks 0-3)
    gemm4<392, 4>(abase + 128, pw1, 4, w, lane, acc);  // agg_hi (W ks 4-7)
    gemm4<392, 4>(abase + 256, pw1, 4, w, lane, acc);  // agg_lo (same W ks 4-7)
  }
  __syncthreads();

  // ---- Phase C: bias1 + SiLU -> sH (overlays sN, stride 136)
  {
    const int colb = w * 32;
#pragma unroll
    for (int cf = 0; cf < 2; ++cf) {
      const int col = colb + cf * 16 + (lane & 15);
      const float bias = b1[col];
#pragma unroll
      for (int rf = 0; rf < 4; ++rf) {
#pragma unroll
        for (int jj = 0; jj < 4; ++jj) {
          const int row = rf * 16 + ((lane >> 4) << 2) + jj;
          float vv = acc[rf][cf][jj] + bias;
          float h = vv / (1.f + __expf(-vv));
          sN[row * 136 + col] = f2bf(h);
        }
      }
    }
  }
  __syncthreads();

  // ---- Phase D: GEMM2 [64x128] @ [128x128]
  f32x4 acc2[4][2];
#pragma unroll
  for (int rf = 0; rf < 4; ++rf)
#pragma unroll
    for (int cf = 0; cf < 2; ++cf) acc2[rf][cf] = 0.f;
  {
    const u16* abase = sN + (lane & 15) * 136 + ((lane >> 4) << 3);
    gemm4<136, 4>(abase, pw2, 0, w, lane, acc2);
  }
  __syncthreads();

  // ---- Phase E: Y = acc2 + b2 -> sY (stride 133)
  {
    const int colb = w * 32;
#pragma unroll
    for (int cf = 0; cf < 2; ++cf) {
      const int col = colb + cf * 16 + (lane & 15);
      const float bias = b2[col];
#pragma unroll
      for (int rf = 0; rf < 4; ++rf) {
#pragma unroll
        for (int jj = 0; jj < 4; ++jj) {
          const int row = rf * 16 + ((lane >> 4) << 2) + jj;
          sY[row * 133 + col] = acc2[rf][cf][jj] + bias;
        }
      }
    }
  }
  __syncthreads();

  // ---- Phase F: LayerNorm + residual; lane j owns cols [32j, 32j+32)
  if (nv) {
    const int cb = 32 * j;
    float vals[32];
    float sum = 0.f, sq = 0.f;
#pragma unroll
    for (int i = 0; i < 32; ++i) {
      float vv = sY[r * 133 + cb + i];
      vals[i] = vv;
      sum += vv;
      sq += vv * vv;
    }
    sum += __shfl_xor(sum, 1);
    sum += __shfl_xor(sum, 2);
    sq += __shfl_xor(sq, 1);
    sq += __shfl_xor(sq, 2);
    const float mu = sum * (1.f / 128.f);
    const float rs = rsqrtf(sq * (1.f / 128.f) - mu * mu + 1e-5f);
    const float* xrow = x + (size_t)n * 128 + cb;
    float* orow = outx + (size_t)n * 128 + cb;
#pragma unroll
    for (int qq = 0; qq < 8; ++qq) {
      float4 xv = *(const float4*)(xrow + 4 * qq);
      float4 t4;
      t4.x = xv.x + (vals[4 * qq + 0] - mu) * rs * gln[cb + 4 * qq + 0] + bln[cb + 4 * qq + 0];
      t4.y = xv.y + (vals[4 * qq + 1] - mu) * rs * gln[cb + 4 * qq + 1] + bln[cb + 4 * qq + 1];
      t4.z = xv.z + (vals[4 * qq + 2] - mu) * rs * gln[cb + 4 * qq + 2] + bln[cb + 4 * qq + 2];
      t4.w = xv.w + (vals[4 * qq + 3] - mu) * rs * gln[cb + 4 * qq + 3] + bln[cb + 4 * qq + 3];
      *(float4*)(orow + 4 * qq) = t4;
    }
  }
}

extern "C" void kernel_launch(void* const* d_in, const int* in_sizes, int n_in,
                              void* d_out, int out_size, void* d_ws, size_t ws_size,
                              hipStream_t stream) {
  const float* x = (const float*)d_in[0];
  const float* edge_attr = (const float*)d_in[1];
  const int* ei = (const int*)d_in[2];
  const float* eb_w1 = (const float*)d_in[3];
  const float* eb_b1 = (const float*)d_in[4];
  const float* eb_w2 = (const float*)d_in[5];
  const float* eb_b2 = (const float*)d_in[6];
  const float* eb_g = (const float*)d_in[7];
  const float* eb_beta = (const float*)d_in[8];
  const float* nb_w1 = (const float*)d_in[9];
  const float* nb_b1 = (const float*)d_in[10];
  const float* nb_w2 = (const float*)d_in[11];
  const float* nb_b2 = (const float*)d_in[12];
  const float* nb_g = (const float*)d_in[13];
  const float* nb_beta = (const float*)d_in[14];

  const int N = in_sizes[0] / 128;
  const int E = in_sizes[1] / 128;

  float* out = (float*)d_out;
  float* agg = out;  // MODE 0 only
  float* out_edge = out + (size_t)N * 128;

  // ws layout: packed weights | xbf (bf16 x) | CSR (cnt, roff, cur, elist, bsum) | emsg (bf16)
  u16* pw1e = (u16*)d_ws;
  u16* pw2e = pw1e + 384 * 128;
  u16* pw1n = pw2e + 128 * 128;
  u16* pw2n = pw1n + 256 * 128;
  const size_t w_bytes = (size_t)(384 + 128 + 256 + 128) * 128 * 2;  // 229376
  u16* xbf = (u16*)((char*)d_ws + w_bytes);
  const size_t xbf_bytes = (size_t)N * 128 * 2;
  int* cnt = (int*)((char*)d_ws + w_bytes + xbf_bytes);
  int* roff = cnt + N;
  int* cur = roff + N + 1;
  int* elist = cur + N;
  int* bsum = elist + E;
  const size_t csr_bytes = (size_t)4 * (3 * (size_t)N + 1 + (size_t)E + 512);
  size_t em_off = w_bytes + xbf_bytes + csr_bytes;
  em_off = (em_off + 15) & ~(size_t)15;
  u16* emsg = (u16*)((char*)d_ws + em_off);
  const size_t need_emsg = em_off + (size_t)E * 128 * 2;
  const size_t need_csr = w_bytes + xbf_bytes + csr_bytes;
  const int mode = (ws_size >= need_emsg) ? 2 : ((ws_size >= need_csr) ? 1 : 0);

  pack_all_kernel<<<(14336 + 255) / 256, 256, 0, stream>>>(eb_w1, eb_w2, nb_w1, nb_w2,
                                                           pw1e, pw2e, pw1n, pw2n);

  const int eg = (E + 63) / 64, ng = (N + 63) / 64;
  const int NB = (N + 2047) / 2048;  // <= 512 supported

  if (mode >= 1) {
    const int total8 = N * 16;  // N*128/8
    xcvt_kernel<<<(total8 + 255) / 256, 256, 0, stream>>>(x, xbf, total8);
    hipMemsetAsync(cnt, 0, (size_t)N * 4, stream);
    if (mode == 2) {
      edge_kernel<2><<<eg, 256, 0, stream>>>(x, xbf, edge_attr, ei, pw1e, pw2e, eb_b1,
                                             eb_b2, eb_g, eb_beta, out_edge, agg, emsg, cnt, E);
    } else {
      edge_kernel<1><<<eg, 256, 0, stream>>>(x, xbf, edge_attr, ei, pw1e, pw2e, eb_b1,
                                             eb_b2, eb_g, eb_beta, out_edge, agg, emsg, cnt, E);
    }
    scan1_kernel<<<NB, 256, 0, stream>>>(cnt, bsum, N);
    scan2_kernel<<<1, 512, 0, stream>>>(bsum, roff, NB, N, E);
    scan3_kernel<<<NB, 256, 0, stream>>>(cnt, bsum, roff, cur, N);
    fill_kernel<<<(E + 255) / 256, 256, 0, stream>>>(ei, cur, elist, E);
    if (mode == 2) {
      node_kernel<2><<<ng, 256, 0, stream>>>(x, xbf, nullptr, roff, elist, emsg, nullptr,
                                             nullptr, pw1n, pw2n, nb_b1, nb_b2, nb_g,
                                             nb_beta, out, N);
    } else {
      node_kernel<1><<<ng, 256, 0, stream>>>(x, xbf, nullptr, roff, elist, nullptr, out_edge,
                                             edge_attr, pw1n, pw2n, nb_b1, nb_b2, nb_g,
                                             nb_beta, out, N);
    }
  } else {
    hipMemsetAsync(agg, 0, (size_t)N * 128 * sizeof(float), stream);
    edge_kernel<0><<<eg, 256, 0, stream>>>(x, nullptr, edge_attr, ei, pw1e, pw2e, eb_b1,
                                           eb_b2, eb_g, eb_beta, out_edge, agg, emsg, cnt, E);
    node_kernel<0><<<ng, 256, 0, stream>>>(x, nullptr, agg, nullptr, nullptr, nullptr,
                                           nullptr, nullptr, pw1n, pw2n, nb_b1, nb_b2,
                                           nb_g, nb_beta, out, N);
  }
}